// Round 14
// baseline (5330.565 us; speedup 1.0000x reference)
//
#include <hip/hip_runtime.h>

constexpr int B = 32, L = 1024, D = 512, H = 512;

// ---- LDS byte offsets ----
// A tiles [16 rows][512 k] bf16 — rows 0..3 = batches, rows 4..15 zero.
constexpr int AH_HI = 0;
constexpr int AH_LO = 16384;
constexpr int AX_OFF = 32768;
// B tiles [16 n][512 k] bf16 — n = member's 16 output features.
constexpr int BHZ = 49152, BHR = 65536, BHC = 81920;
constexpr int BXZ = 98304, BXR = 114688, BXC = 131072;
constexpr size_t SMEM_BYTES = 147456;   // 144 KiB (no C buffer needed)

// ---- workspace (dword offsets) ----
// hrec: [parity(2)][ring(8)][member(32)][64] u32, layout [feature(16)][batch(4)]
//       value = (bf16_hi << 16) | bf16_lo of h
constexpr int HREC_OFF = 0;          // 32768 dw = 128 KiB
constexpr int FLAGS_OFF = 32768;     // [ring(8)][member(32)] stride 32 dw

typedef __attribute__((ext_vector_type(8))) short short8v;
typedef __attribute__((ext_vector_type(4))) float f32x4;
using ull = unsigned long long;

__device__ __forceinline__ unsigned short f2bf(float f) {   // RNE f32->bf16
    unsigned u = __float_as_uint(f);
    return (unsigned short)((u + 0x7FFFu + ((u >> 16) & 1u)) >> 16);
}
__device__ __forceinline__ float bf2f(unsigned short b) {
    return __uint_as_float((unsigned)b << 16);
}
// XOR-swizzled byte address within a [row][1024B] tile
__device__ __forceinline__ int aswz(int row, int kbyte) {
    return row * 1024 + (kbyte ^ ((row & 7) << 4));
}
__device__ __forceinline__ unsigned ld_agent32(const unsigned* p) {
    return __hip_atomic_load(p, __ATOMIC_RELAXED, __HIP_MEMORY_SCOPE_AGENT);
}
__device__ __forceinline__ ull ld_agent64(const ull* p) {
    return __hip_atomic_load(p, __ATOMIC_RELAXED, __HIP_MEMORY_SCOPE_AGENT);
}
__device__ __forceinline__ void st_agent32(unsigned* p, unsigned v) {
    __hip_atomic_store(p, v, __ATOMIC_RELAXED, __HIP_MEMORY_SCOPE_AGENT);
}
__device__ __forceinline__ void st_agent64(ull* p, ull v) {
    __hip_atomic_store(p, v, __ATOMIC_RELAXED, __HIP_MEMORY_SCOPE_AGENT);
}

__global__ __launch_bounds__(64, 1)
void gru_1w(const float* __restrict__ x, const float* __restrict__ h0,
            const float* __restrict__ Wxz, const float* __restrict__ Whz,
            const float* __restrict__ bz,
            const float* __restrict__ Wxr, const float* __restrict__ Whr,
            const float* __restrict__ br,
            const float* __restrict__ Wxh, const float* __restrict__ Whh,
            const float* __restrict__ bh,
            float* __restrict__ out, unsigned* __restrict__ ws)
{
    extern __shared__ char smem[];

    const int tid = threadIdx.x;     // one wave: tid == lane
    const int bid = blockIdx.x;
    // ring g = XCD residue (round-robin dispatch): all 32 members co-XCD
    const int g  = bid & 7;          // ring: batches g*4 .. g*4+3
    const int fc = bid >> 3;         // member 0..31: features fc*16 .. +15
    const int F0 = fc * 16;

    unsigned* hrec  = ws + HREC_OFF;
    unsigned* fring = ws + FLAGS_OFF + g * 32 * 32;

    // ---- zero the A region (rows 4..15 must stay zero) ----
    for (int i = tid; i < 3072; i += 64)
        *(uint4*)(smem + i * 16) = make_uint4(0, 0, 0, 0);
    __syncthreads();

    // ---- one-time weight staging: 6 bf16 B-tiles, swizzled [n][k] ----
    {
        const float* WSRC[6] = {Whz, Whr, Whh, Wxz, Wxr, Wxh};
        const int    BOFF[6] = {BHZ, BHR, BHC, BXZ, BXR, BXC};
        for (int s6 = 0; s6 < 6; ++s6) {
            const float* W = WSRC[s6];
            char* bb = smem + BOFF[s6];
            for (int rep = 0; rep < 8; ++rep) {
                const int k = rep * 64 + tid;
                const float* src = W + (size_t)k * H + F0;
                const float4 a = *(const float4*)(src);
                const float4 b4 = *(const float4*)(src + 4);
                const float4 c4 = *(const float4*)(src + 8);
                const float4 d4 = *(const float4*)(src + 12);
                const float v[16] = {a.x, a.y, a.z, a.w, b4.x, b4.y, b4.z, b4.w,
                                     c4.x, c4.y, c4.z, c4.w, d4.x, d4.y, d4.z, d4.w};
#pragma unroll
                for (int f = 0; f < 16; ++f)
                    *(unsigned short*)(bb + aswz(f, k * 2)) = f2bf(v[f]);
            }
        }
    }

    // ---- per-thread roles ----
    // h ingest: member hm = tid>>1, half hh = tid&1 (32 records = 16 ull)
    const int hm = tid >> 1, hh = tid & 1;
    // x staging: row xrow = tid&3 (ring-local batch), 32 cols from xcb
    const int xrow = tid & 3;
    const int xcb  = (tid >> 2) * 32;
    // MFMA: lane rc = A/B row, kb = 16B k-sub; single wave covers K=512
    const int rc = tid & 15;
    const int kb = tid >> 4;
    int offk[16];
#pragma unroll
    for (int ks = 0; ks < 16; ++ks)
        offk[ks] = aswz(rc, ks * 64 + kb * 16);
    // epilogue: lanes 0..15 own feature F0+tid across batches 0..3 (in regs)
    float bzv = 0.f, brv = 0.f, bhv = 0.f;
    float hold[4] = {0.f, 0.f, 0.f, 0.f};
    if (tid < 16) {
        bzv = bz[F0 + tid]; brv = br[F0 + tid]; bhv = bh[F0 + tid];
        unsigned rec[4];
#pragma unroll
        for (int b2 = 0; b2 < 4; ++b2) {
            hold[b2] = h0[(g * 4 + b2) * H + F0 + tid];
            const unsigned hi = f2bf(hold[b2]);
            const unsigned lo = f2bf(hold[b2] - bf2f((unsigned short)hi));
            rec[b2] = (hi << 16) | lo;
        }
        ull* rp = (ull*)&hrec[((0 * 8 + g) * 32 + fc) * 64 + tid * 4];
        st_agent64(rp,     ((ull)rec[1] << 32) | rec[0]);
        st_agent64(rp + 1, ((ull)rec[3] << 32) | rec[2]);
    }
    asm volatile("s_waitcnt vmcnt(0)" ::: "memory");
    if (tid == 0)
        st_agent32(&fring[fc * 32], 1u);

    // prefetch x(0): 32 floats/thread
    float4 xq[8];
    {
        const float* xp = x + ((size_t)(g * 4 + xrow) * L + 0) * D + xcb;
#pragma unroll
        for (int c = 0; c < 8; ++c) xq[c] = *(const float4*)(xp + 4 * c);
    }

    for (int t = 0; t < L; ++t) {
        // ---- stage x(t) as bf16 into AX (absorbed by the poll wait) ----
        {
            float xv[32];
#pragma unroll
            for (int c = 0; c < 8; ++c) {
                xv[4 * c + 0] = xq[c].x; xv[4 * c + 1] = xq[c].y;
                xv[4 * c + 2] = xq[c].z; xv[4 * c + 3] = xq[c].w;
            }
            unsigned wd[16];
#pragma unroll
            for (int j = 0; j < 16; ++j)
                wd[j] = (unsigned)f2bf(xv[2 * j]) |
                        ((unsigned)f2bf(xv[2 * j + 1]) << 16);
#pragma unroll
            for (int c = 0; c < 4; ++c)
                *(uint4*)(smem + AX_OFF + aswz(xrow, xcb * 2 + c * 16)) =
                    make_uint4(wd[4 * c], wd[4 * c + 1], wd[4 * c + 2], wd[4 * c + 3]);
        }

        // ---- per-member decoupled ingest: poll own member's single flag,
        //      issue the 128B record load the moment it goes fresh ----
        const unsigned s = (unsigned)(t + 1);
        ull qd[16];
        {
            const unsigned* fp = fring + hm * 32;
            const ull* rb = (const ull*)&hrec[(((t & 1) * 8 + g) * 32 + hm) * 64] + hh * 16;
            bool pending = true;
            do {
                if (pending) {
                    const unsigned v = ld_agent32(fp);
                    if ((v - s) <= 1u) {
#pragma unroll
                        for (int i = 0; i < 16; ++i) qd[i] = ld_agent64(rb + i);
                        pending = false;
                    }
                }
            } while (__any(pending));
        }
        // unpack: thread covers features hh*8..+7 (kbyte base hm*32+hh*16),
        // batches 0..3; record (f_local j, b) = u32 idx j*4+b
        {
            const int kbyte = hm * 32 + hh * 16;
#pragma unroll
            for (int b2 = 0; b2 < 4; ++b2) {
                unsigned v[8];
#pragma unroll
                for (int j = 0; j < 8; ++j) {
                    const ull qq = qd[j * 2 + (b2 >> 1)];
                    v[j] = (b2 & 1) ? (unsigned)(qq >> 32) : (unsigned)qq;
                }
                uint4 hi4, lo4;
                hi4.x = (v[0] >> 16) | (v[1] & 0xFFFF0000u);
                hi4.y = (v[2] >> 16) | (v[3] & 0xFFFF0000u);
                hi4.z = (v[4] >> 16) | (v[5] & 0xFFFF0000u);
                hi4.w = (v[6] >> 16) | (v[7] & 0xFFFF0000u);
                lo4.x = (v[0] & 0xFFFFu) | (v[1] << 16);
                lo4.y = (v[2] & 0xFFFFu) | (v[3] << 16);
                lo4.z = (v[4] & 0xFFFFu) | (v[5] << 16);
                lo4.w = (v[6] & 0xFFFFu) | (v[7] << 16);
                *(uint4*)(smem + AH_HI + aswz(b2, kbyte)) = hi4;
                *(uint4*)(smem + AH_LO + aswz(b2, kbyte)) = lo4;
            }
        }
        __syncthreads();   // single-wave barrier: LDS writes -> MFMA reads

        // ---- MFMA: full K=512 in one wave, 16 k-steps × 9, interleaved ----
        f32x4 az = {0,0,0,0}, ar = {0,0,0,0}, ach = {0,0,0,0}, acx = {0,0,0,0};
#pragma unroll
        for (int ks = 0; ks < 16; ++ks) {
            const int o = offk[ks];
            const short8v ahh = *(const short8v*)(smem + AH_HI + o);
            const short8v ahl = *(const short8v*)(smem + AH_LO + o);
            const short8v axv = *(const short8v*)(smem + AX_OFF + o);
            const short8v bz_ = *(const short8v*)(smem + BHZ + o);
            const short8v br_ = *(const short8v*)(smem + BHR + o);
            const short8v bc_ = *(const short8v*)(smem + BHC + o);
            const short8v xz_ = *(const short8v*)(smem + BXZ + o);
            const short8v xr_ = *(const short8v*)(smem + BXR + o);
            const short8v xc_ = *(const short8v*)(smem + BXC + o);
            az  = __builtin_amdgcn_mfma_f32_16x16x32_bf16(ahh, bz_, az, 0, 0, 0);
            ar  = __builtin_amdgcn_mfma_f32_16x16x32_bf16(ahh, br_, ar, 0, 0, 0);
            ach = __builtin_amdgcn_mfma_f32_16x16x32_bf16(ahh, bc_, ach, 0, 0, 0);
            az  = __builtin_amdgcn_mfma_f32_16x16x32_bf16(ahl, bz_, az, 0, 0, 0);
            ar  = __builtin_amdgcn_mfma_f32_16x16x32_bf16(ahl, br_, ar, 0, 0, 0);
            ach = __builtin_amdgcn_mfma_f32_16x16x32_bf16(ahl, bc_, ach, 0, 0, 0);
            az  = __builtin_amdgcn_mfma_f32_16x16x32_bf16(axv, xz_, az, 0, 0, 0);
            ar  = __builtin_amdgcn_mfma_f32_16x16x32_bf16(axv, xr_, ar, 0, 0, 0);
            acx = __builtin_amdgcn_mfma_f32_16x16x32_bf16(axv, xc_, acx, 0, 0, 0);
        }

        // ---- epilogue straight from registers: lane<16 = feature, reg = batch
        //      (C layout: col=lane&15, row=(lane>>4)*4+reg -> lanes 0..15 hold
        //       rows 0..3 = batches in regs 0..3) ----
        if (tid < 16) {
            unsigned rec[4];
#pragma unroll
            for (int b2 = 0; b2 < 4; ++b2) {
                const float z = 1.f / (1.f + __expf(-(az[b2] + bzv)));
                const float r = 1.f / (1.f + __expf(-(ar[b2] + brv)));
                const float pre = acx[b2] + r * (ach[b2] + bhv);
                const float e = __expf(-2.f * fabsf(pre));
                float th = (1.f - e) / (1.f + e);
                th = (pre < 0.f) ? -th : th;
                const float hnv = z * hold[b2] + (1.f - z) * th;
                hold[b2] = hnv;
                const unsigned hi = f2bf(hnv);
                const unsigned lo = f2bf(hnv - bf2f((unsigned short)hi));
                rec[b2] = (hi << 16) | lo;
            }
            ull* rp = (ull*)&hrec[((((t + 1) & 1) * 8 + g) * 32 + fc) * 64 + tid * 4];
            st_agent64(rp,     ((ull)rec[1] << 32) | rec[0]);
            st_agent64(rp + 1, ((ull)rec[3] << 32) | rec[2]);
        }
        // drain record stores, publish the member's single flag
        asm volatile("s_waitcnt vmcnt(0)" ::: "memory");
        if (tid == 0)
            st_agent32(&fring[fc * 32], s + 1u);
        __syncthreads();   // ~free (1 wave): orders MFMA LDS reads before
                           // next iteration's AX/AH overwrites

        // out writes off the critical path
        if (tid < 16) {
#pragma unroll
            for (int b2 = 0; b2 < 4; ++b2) {
                out[((size_t)(g * 4 + b2) * L + t) * H + F0 + tid] = hold[b2];
                if (t == L - 1)
                    out[(size_t)B * L * H + (size_t)(g * 4 + b2) * H + F0 + tid] = hold[b2];
            }
        }

        // prefetch x(t+1); latency hides under next step's poll
        if (t + 1 < L) {
            const float* xp = x + ((size_t)(g * 4 + xrow) * L + (t + 1)) * D + xcb;
#pragma unroll
            for (int c = 0; c < 8; ++c) xq[c] = *(const float4*)(xp + 4 * c);
        }
    }
}

extern "C" void kernel_launch(void* const* d_in, const int* in_sizes, int n_in,
                              void* d_out, int out_size, void* d_ws, size_t ws_size,
                              hipStream_t stream) {
    const float* x   = (const float*)d_in[0];
    const float* h0  = (const float*)d_in[1];
    const float* Wxz = (const float*)d_in[2];
    const float* Whz = (const float*)d_in[3];
    const float* bz  = (const float*)d_in[4];
    const float* Wxr = (const float*)d_in[5];
    const float* Whr = (const float*)d_in[6];
    const float* br  = (const float*)d_in[7];
    const float* Wxh = (const float*)d_in[8];
    const float* Whh = (const float*)d_in[9];
    const float* bh  = (const float*)d_in[10];
    float* out = (float*)d_out;
    unsigned* ws = (unsigned*)d_ws;

    (void)hipFuncSetAttribute((const void*)gru_1w,
                              hipFuncAttributeMaxDynamicSharedMemorySize,
                              (int)SMEM_BYTES);

    void* args[] = {(void*)&x, (void*)&h0, (void*)&Wxz, (void*)&Whz, (void*)&bz,
                    (void*)&Wxr, (void*)&Whr, (void*)&br, (void*)&Wxh, (void*)&Whh,
                    (void*)&bh, (void*)&out, (void*)&ws};
    hipError_t err = hipLaunchCooperativeKernel((void*)gru_1w, dim3(256),
                                                dim3(64), args,
                                                (unsigned)SMEM_BYTES, stream);
    if (err != hipSuccess) {
        // kernel uses only its own flag barrier; 256 blocks at 1/CU are
        // trivially co-resident, so a plain launch is a safe fallback
        gru_1w<<<dim3(256), dim3(64), SMEM_BYTES, stream>>>(
            x, h0, Wxz, Whz, bz, Wxr, Whr, br, Wxh, Whh, bh, out, ws);
    }
}